// Round 3
// baseline (229.848 us; speedup 1.0000x reference)
//
#include <hip/hip_runtime.h>
#include <math.h>

// Problem constants
#define B 512
#define E 256
#define L 1024  // 32*32

typedef float f32x4 __attribute__((ext_vector_type(4)));

// Workspace layout (floats)
#define O_DIST 0u            // B*L
#define O_H    524288u       // B*L   (eta-scaled h)
#define O_Q    1048576u      // B*L   (raw_q)
#define O_SOMN 1572864u      // L*E
#define O_IRS  1835008u      // B     (1/rowsum)
#define O_CS   1835520u      // L     (colsum of normalized q)

// ---------------------------------------------------------------------------
// K1/K5: tiled squared-distance matrix out[b, j]
// MODE 0: dist^2.  MODE 1: raw_q = 1/(1+sqrt(dist^2)).
// 64x64 tiles, K-chunks of 64 over E=256, 256 threads, 4x4 micro-tile.
// ---------------------------------------------------------------------------
template <int MODE>
__global__ __launch_bounds__(256) void dist_kernel(const float* __restrict__ Zg,
                                                   const float* __restrict__ Wg,
                                                   float* __restrict__ out) {
    __shared__ float Zs[64][67];
    __shared__ float Ws[64][67];
    const int tid = threadIdx.x;
    const int tb = blockIdx.x >> 4;   // 0..7
    const int tn = blockIdx.x & 15;   // 0..15
    const int b0 = tb * 64, n0 = tn * 64;
    const int ty = tid >> 4, tx = tid & 15;

    float acc[4][4];
#pragma unroll
    for (int i = 0; i < 4; ++i)
#pragma unroll
        for (int j = 0; j < 4; ++j) acc[i][j] = 0.f;

    for (int kc = 0; kc < E; kc += 64) {
        const int c4 = tx * 4;
#pragma unroll
        for (int s = 0; s < 4; ++s) {
            const int r = ty + 16 * s;
            float4 zv = *(const float4*)(Zg + (size_t)(b0 + r) * E + kc + c4);
            Zs[r][c4 + 0] = zv.x; Zs[r][c4 + 1] = zv.y;
            Zs[r][c4 + 2] = zv.z; Zs[r][c4 + 3] = zv.w;
            float4 wv = *(const float4*)(Wg + (size_t)(n0 + r) * E + kc + c4);
            Ws[r][c4 + 0] = wv.x; Ws[r][c4 + 1] = wv.y;
            Ws[r][c4 + 2] = wv.z; Ws[r][c4 + 3] = wv.w;
        }
        __syncthreads();
#pragma unroll 4
        for (int k = 0; k < 64; ++k) {
            float zr[4], wr[4];
#pragma unroll
            for (int i = 0; i < 4; ++i) zr[i] = Zs[ty * 4 + i][k];
#pragma unroll
            for (int j = 0; j < 4; ++j) wr[j] = Ws[tx * 4 + j][k];
#pragma unroll
            for (int i = 0; i < 4; ++i)
#pragma unroll
                for (int j = 0; j < 4; ++j) {
                    float d = zr[i] - wr[j];
                    acc[i][j] = fmaf(d, d, acc[i][j]);
                }
        }
        __syncthreads();
    }
#pragma unroll
    for (int i = 0; i < 4; ++i) {
        const int b = b0 + ty * 4 + i;
        float4 v;
        float r0 = acc[i][0], r1 = acc[i][1], r2 = acc[i][2], r3 = acc[i][3];
        if (MODE == 1) {
            r0 = 1.f / (1.f + sqrtf(r0));
            r1 = 1.f / (1.f + sqrtf(r1));
            r2 = 1.f / (1.f + sqrtf(r2));
            r3 = 1.f / (1.f + sqrtf(r3));
        }
        v.x = r0; v.y = r1; v.z = r2; v.w = r3;
        *(float4*)(out + (size_t)b * L + n0 + tx * 4) = v;
    }
}

// K2: fused per-row argmin (first-index tie-break) + neighborhood h row write
__global__ __launch_bounds__(256) void argmin_h_kernel(const float* __restrict__ dist,
                                                       const int* __restrict__ step,
                                                       float* __restrict__ h) {
    const int b = blockIdx.x;
    const int tid = threadIdx.x;
    float best = 3.4e38f;
    int bi = 0;
#pragma unroll
    for (int s = 0; s < 4; ++s) {
        const int j = tid + s * 256;           // increasing j -> first-min per thread
        const float v = dist[(size_t)b * L + j];
        if (v < best) { best = v; bi = j; }
    }
    __shared__ float sv[256];
    __shared__ int si[256];
    sv[tid] = best; si[tid] = bi;
    __syncthreads();
    for (int s = 128; s > 0; s >>= 1) {
        if (tid < s) {
            float ov = sv[tid + s]; int oi = si[tid + s];
            if (ov < sv[tid] || (ov == sv[tid] && oi < si[tid])) { sv[tid] = ov; si[tid] = oi; }
        }
        __syncthreads();
    }
    __shared__ int su;
    if (tid == 0) su = si[0];
    __syncthreads();

    const int u = su;
    const int ur = u >> 5, uc = u & 31;
    const float n = (float)step[0];
    const float decay = expf(-n * 0.01f);
    const float eta = 0.3f * decay;
    const float sigma = 16.0f * decay;
    const float inv2s2 = 1.0f / (2.0f * sigma * sigma);
#pragma unroll
    for (int s = 0; s < 4; ++s) {
        const int t = tid + s * 256;
        const int i = t >> 5, j = t & 31;
        const float dr = (float)(ur - i), dc = (float)(uc - j);
        h[(size_t)b * L + t] = eta * expf(-(dr * dr + dc * dc) * inv2s2);
    }
}

// K3: delta[b, hw, e] = h_s[b,hw] * (Z[b,e] - SOM[hw,e])   — the 537 MB writer.
// grid = 512 b x 8 chunks = 4096 blocks; each wave owns one hw per iteration,
// 32 iterations x 1KB nontemporal store per wave. Z row loaded once per thread.
__global__ __launch_bounds__(256) void delta_kernel(const float* __restrict__ Zg,
                                                    const float* __restrict__ Wg,
                                                    const float* __restrict__ h,
                                                    float* __restrict__ delta) {
    const int b = blockIdx.x >> 3;
    const int hw0 = (blockIdx.x & 7) << 7;   // 128 hw per block
    const int quad = threadIdx.x >> 6;       // wave id 0..3
    const int lane = threadIdx.x & 63;
    const float4 z = *(const float4*)(Zg + (size_t)b * E + lane * 4);
    const float* __restrict__ hrow = h + (size_t)b * L + hw0;
#pragma unroll 8
    for (int it = 0; it < 32; ++it) {
        const int hwo = it * 4 + quad;
        const float hs = hrow[hwo];          // wave-uniform broadcast
        const float4 w = *(const float4*)(Wg + (size_t)(hw0 + hwo) * E + lane * 4);
        f32x4 o;
        o.x = hs * (z.x - w.x);
        o.y = hs * (z.y - w.y);
        o.z = hs * (z.z - w.z);
        o.w = hs * (z.w - w.w);
        f32x4* dst = (f32x4*)(delta + ((size_t)b * L + hw0 + hwo) * E + lane * 4);
        __builtin_nontemporal_store(o, dst);
    }
}

// K4: SOM_new[hw,e] = SOM + (1/B) * (sum_b h_s*Z - (sum_b h_s) * SOM)
// 1024 blocks (one hw each), 256 threads (e).
__global__ __launch_bounds__(256) void update_kernel(const float* __restrict__ Zg,
                                                     const float* __restrict__ Wg,
                                                     const float* __restrict__ h,
                                                     float* __restrict__ somn) {
    const int hw = blockIdx.x;
    const int e = threadIdx.x;
    float acc = 0.f, hsum = 0.f;
#pragma unroll 8
    for (int b = 0; b < B; ++b) {
        const float hv = h[(size_t)b * L + hw];
        acc = fmaf(hv, Zg[(size_t)b * E + e], acc);
        hsum += hv;
    }
    const float w = Wg[(size_t)hw * E + e];
    somn[(size_t)hw * E + e] = w + (1.0f / (float)B) * (acc - hsum * w);
}

// K6: irs[b] = 1 / sum_j raw_q[b, j]
__global__ __launch_bounds__(256) void rowsum_kernel(const float* __restrict__ q,
                                                     float* __restrict__ irs) {
    const int b = blockIdx.x;
    const int tid = threadIdx.x;
    float acc = 0.f;
#pragma unroll
    for (int s = 0; s < 4; ++s) acc += q[(size_t)b * L + tid + s * 256];
    __shared__ float sm[256];
    sm[tid] = acc;
    __syncthreads();
    for (int st = 128; st > 0; st >>= 1) {
        if (tid < st) sm[tid] += sm[tid + st];
        __syncthreads();
    }
    if (tid == 0) irs[b] = 1.0f / sm[0];
}

// K7: cs[j] = sum_b raw_q[b,j] * irs[b]
__global__ __launch_bounds__(256) void colsum_kernel(const float* __restrict__ q,
                                                     const float* __restrict__ irs,
                                                     float* __restrict__ cs) {
    const int j = blockIdx.x * 256 + threadIdx.x;  // 4 blocks
    float acc = 0.f;
#pragma unroll 8
    for (int b = 0; b < B; ++b) acc = fmaf(q[(size_t)b * L + j], irs[b], acc);
    cs[j] = acc;
}

// K8: kl[b] = T/S - log(S);  S = sum_j rp,  T = sum_j rp*log(qq/cs[j])
__global__ __launch_bounds__(256) void kl_kernel(const float* __restrict__ q,
                                                 const float* __restrict__ irs,
                                                 const float* __restrict__ cs,
                                                 float* __restrict__ kl) {
    const int b = blockIdx.x;
    const int tid = threadIdx.x;
    const float irsb = irs[b];
    float S = 0.f, T = 0.f;
#pragma unroll
    for (int s = 0; s < 4; ++s) {
        const int j = tid + s * 256;
        const float qq = q[(size_t)b * L + j] * irsb;
        const float ic = 1.0f / cs[j];
        const float rp = qq * qq * ic;
        S += rp;
        T = fmaf(rp, logf(qq * ic), T);
    }
    __shared__ float sS[256], sT[256];
    sS[tid] = S; sT[tid] = T;
    __syncthreads();
    for (int st = 128; st > 0; st >>= 1) {
        if (tid < st) { sS[tid] += sS[tid + st]; sT[tid] += sT[tid + st]; }
        __syncthreads();
    }
    if (tid == 0) kl[b] = sT[0] / sS[0] - logf(sS[0]);
}

extern "C" void kernel_launch(void* const* d_in, const int* in_sizes, int n_in,
                              void* d_out, int out_size, void* d_ws, size_t ws_size,
                              hipStream_t stream) {
    const float* Zg = (const float*)d_in[0];
    const float* Wg = (const float*)d_in[1];
    const int* step = (const int*)d_in[2];
    float* out = (float*)d_out;          // [0,512): kl_loss, [512,...): delta
    float* ws = (float*)d_ws;

    float* dist = ws + O_DIST;
    float* h    = ws + O_H;
    float* q    = ws + O_Q;
    float* somn = ws + O_SOMN;
    float* irs  = ws + O_IRS;
    float* cs   = ws + O_CS;

    float* kl    = out;
    float* delta = out + B;

    hipLaunchKernelGGL((dist_kernel<0>), dim3(128), dim3(256), 0, stream, Zg, Wg, dist);
    hipLaunchKernelGGL(argmin_h_kernel, dim3(B), dim3(256), 0, stream, dist, step, h);
    hipLaunchKernelGGL(delta_kernel, dim3(4096), dim3(256), 0, stream, Zg, Wg, h, delta);
    hipLaunchKernelGGL(update_kernel, dim3(L), dim3(256), 0, stream, Zg, Wg, h, somn);
    hipLaunchKernelGGL((dist_kernel<1>), dim3(128), dim3(256), 0, stream, Zg, somn, q);
    hipLaunchKernelGGL(rowsum_kernel, dim3(B), dim3(256), 0, stream, q, irs);
    hipLaunchKernelGGL(colsum_kernel, dim3(L / 256), dim3(256), 0, stream, q, irs, cs);
    hipLaunchKernelGGL(kl_kernel, dim3(B), dim3(256), 0, stream, q, irs, cs, kl);
}

// Round 4
// 201.655 us; speedup vs baseline: 1.1398x; 1.1398x over previous
//
#include <hip/hip_runtime.h>
#include <math.h>

// Problem constants
#define B 512
#define E 256
#define L 1024  // 32*32

typedef float f32x4 __attribute__((ext_vector_type(4)));

// Workspace layout (floats)
#define O_DIST 0u            // B*L   (dist^2; dead after argmin_h -> reused for colsum partials)
#define O_H    524288u       // B*L   (eta-scaled h)
#define O_Q    1048576u      // B*L   (raw_q)
#define O_SOMN 1572864u      // L*E
#define O_IRS  1835008u      // B     (1/rowsum)
#define O_PART O_DIST        // 16*L  colsum partials (overlays dead dist)

// ---------------------------------------------------------------------------
// K1/K5: tiled squared-distance matrix out[b, j]
// MODE 0: dist^2.  MODE 1: raw_q = 1/(1+sqrt(dist^2)).
// 64x64 tiles, K-chunks of 64 over E=256, 256 threads, 4x4 micro-tile.
// ---------------------------------------------------------------------------
template <int MODE>
__global__ __launch_bounds__(256) void dist_kernel(const float* __restrict__ Zg,
                                                   const float* __restrict__ Wg,
                                                   float* __restrict__ out) {
    __shared__ float Zs[64][67];
    __shared__ float Ws[64][67];
    const int tid = threadIdx.x;
    const int tb = blockIdx.x >> 4;   // 0..7
    const int tn = blockIdx.x & 15;   // 0..15
    const int b0 = tb * 64, n0 = tn * 64;
    const int ty = tid >> 4, tx = tid & 15;

    float acc[4][4];
#pragma unroll
    for (int i = 0; i < 4; ++i)
#pragma unroll
        for (int j = 0; j < 4; ++j) acc[i][j] = 0.f;

    for (int kc = 0; kc < E; kc += 64) {
        const int c4 = tx * 4;
#pragma unroll
        for (int s = 0; s < 4; ++s) {
            const int r = ty + 16 * s;
            float4 zv = *(const float4*)(Zg + (size_t)(b0 + r) * E + kc + c4);
            Zs[r][c4 + 0] = zv.x; Zs[r][c4 + 1] = zv.y;
            Zs[r][c4 + 2] = zv.z; Zs[r][c4 + 3] = zv.w;
            float4 wv = *(const float4*)(Wg + (size_t)(n0 + r) * E + kc + c4);
            Ws[r][c4 + 0] = wv.x; Ws[r][c4 + 1] = wv.y;
            Ws[r][c4 + 2] = wv.z; Ws[r][c4 + 3] = wv.w;
        }
        __syncthreads();
#pragma unroll 4
        for (int k = 0; k < 64; ++k) {
            float zr[4], wr[4];
#pragma unroll
            for (int i = 0; i < 4; ++i) zr[i] = Zs[ty * 4 + i][k];
#pragma unroll
            for (int j = 0; j < 4; ++j) wr[j] = Ws[tx * 4 + j][k];
#pragma unroll
            for (int i = 0; i < 4; ++i)
#pragma unroll
                for (int j = 0; j < 4; ++j) {
                    float d = zr[i] - wr[j];
                    acc[i][j] = fmaf(d, d, acc[i][j]);
                }
        }
        __syncthreads();
    }
#pragma unroll
    for (int i = 0; i < 4; ++i) {
        const int b = b0 + ty * 4 + i;
        float4 v;
        float r0 = acc[i][0], r1 = acc[i][1], r2 = acc[i][2], r3 = acc[i][3];
        if (MODE == 1) {
            r0 = 1.f / (1.f + sqrtf(r0));
            r1 = 1.f / (1.f + sqrtf(r1));
            r2 = 1.f / (1.f + sqrtf(r2));
            r3 = 1.f / (1.f + sqrtf(r3));
        }
        v.x = r0; v.y = r1; v.z = r2; v.w = r3;
        *(float4*)(out + (size_t)b * L + n0 + tx * 4) = v;
    }
}

// K2: fused per-row argmin (first-index tie-break) + neighborhood h row write
__global__ __launch_bounds__(256) void argmin_h_kernel(const float* __restrict__ dist,
                                                       const int* __restrict__ step,
                                                       float* __restrict__ h) {
    const int b = blockIdx.x;
    const int tid = threadIdx.x;
    float best = 3.4e38f;
    int bi = 0;
#pragma unroll
    for (int s = 0; s < 4; ++s) {
        const int j = tid + s * 256;           // increasing j -> first-min per thread
        const float v = dist[(size_t)b * L + j];
        if (v < best) { best = v; bi = j; }
    }
    __shared__ float sv[256];
    __shared__ int si[256];
    sv[tid] = best; si[tid] = bi;
    __syncthreads();
    for (int s = 128; s > 0; s >>= 1) {
        if (tid < s) {
            float ov = sv[tid + s]; int oi = si[tid + s];
            if (ov < sv[tid] || (ov == sv[tid] && oi < si[tid])) { sv[tid] = ov; si[tid] = oi; }
        }
        __syncthreads();
    }
    __shared__ int su;
    if (tid == 0) su = si[0];
    __syncthreads();

    const int u = su;
    const int ur = u >> 5, uc = u & 31;
    const float n = (float)step[0];
    const float decay = expf(-n * 0.01f);
    const float eta = 0.3f * decay;
    const float sigma = 16.0f * decay;
    const float inv2s2 = 1.0f / (2.0f * sigma * sigma);
#pragma unroll
    for (int s = 0; s < 4; ++s) {
        const int t = tid + s * 256;
        const int i = t >> 5, j = t & 31;
        const float dr = (float)(ur - i), dc = (float)(uc - j);
        h[(size_t)b * L + t] = eta * expf(-(dr * dr + dc * dc) * inv2s2);
    }
}

// K3: delta[b, hw, e] = h_s[b,hw] * (Z[b,e] - SOM[hw,e])   — the 537 MB writer.
// R2-proven structure: 131072 tiny blocks, one 4KB contiguous burst per block.
// Plain (cached) stores this round: full-line streaming writes sustain 6.7 TB/s
// in the fill kernels vs ~5 TB/s we saw with NT.
__global__ __launch_bounds__(256) void delta_kernel(const float* __restrict__ Zg,
                                                    const float* __restrict__ Wg,
                                                    const float* __restrict__ h,
                                                    float* __restrict__ delta) {
    const int bid = blockIdx.x;              // 512 * 256 blocks
    const int b = bid >> 8;
    const int hw = ((bid & 255) << 2) + (threadIdx.x >> 6);
    const int lane = threadIdx.x & 63;
    const float hs = h[(size_t)b * L + hw];
    const float4 z = *(const float4*)(Zg + (size_t)b * E + lane * 4);
    const float4 w = *(const float4*)(Wg + (size_t)hw * E + lane * 4);
    f32x4 o;
    o.x = hs * (z.x - w.x);
    o.y = hs * (z.y - w.y);
    o.z = hs * (z.z - w.z);
    o.w = hs * (z.w - w.w);
    *(f32x4*)(delta + ((size_t)b * L + hw) * E + lane * 4) = o;
}

// K4: SOM_new[hw,e] = SOM + (1/B) * (sum_b h_s*Z - (sum_b h_s) * SOM)  (R2 form)
__global__ __launch_bounds__(256) void update_kernel(const float* __restrict__ Zg,
                                                     const float* __restrict__ Wg,
                                                     const float* __restrict__ h,
                                                     float* __restrict__ somn) {
    const int hw0 = blockIdx.x * 4;  // 256 blocks
    const int e = threadIdx.x;
    float a0 = 0.f, a1 = 0.f, a2 = 0.f, a3 = 0.f;
    float s0 = 0.f, s1 = 0.f, s2 = 0.f, s3 = 0.f;
    for (int b = 0; b < B; ++b) {
        const float z = Zg[(size_t)b * E + e];
        const float4 hv = *(const float4*)(h + (size_t)b * L + hw0);
        a0 = fmaf(hv.x, z, a0); s0 += hv.x;
        a1 = fmaf(hv.y, z, a1); s1 += hv.y;
        a2 = fmaf(hv.z, z, a2); s2 += hv.z;
        a3 = fmaf(hv.w, z, a3); s3 += hv.w;
    }
    const float c = 1.0f / (float)B;
    float w, acc[4] = {a0, a1, a2, a3}, ss[4] = {s0, s1, s2, s3};
#pragma unroll
    for (int l = 0; l < 4; ++l) {
        w = Wg[(size_t)(hw0 + l) * E + e];
        somn[(size_t)(hw0 + l) * E + e] = w + c * (acc[l] - ss[l] * w);
    }
}

// K6: irs[b] = 1 / sum_j raw_q[b, j]
__global__ __launch_bounds__(256) void rowsum_kernel(const float* __restrict__ q,
                                                     float* __restrict__ irs) {
    const int b = blockIdx.x;
    const int tid = threadIdx.x;
    float acc = 0.f;
#pragma unroll
    for (int s = 0; s < 4; ++s) acc += q[(size_t)b * L + tid + s * 256];
    __shared__ float sm[256];
    sm[tid] = acc;
    __syncthreads();
    for (int st = 128; st > 0; st >>= 1) {
        if (tid < st) sm[tid] += sm[tid + st];
        __syncthreads();
    }
    if (tid == 0) irs[b] = 1.0f / sm[0];
}

// K7: colsum partials: part[c][j] = sum_{b in chunk c} q[b][j]*irs[b]
// 64 blocks (16 b-chunks x 4 j-tiles) -> 16x more CUs than the old 4-block form.
__global__ __launch_bounds__(256) void colsum_part_kernel(const float* __restrict__ q,
                                                          const float* __restrict__ irs,
                                                          float* __restrict__ part) {
    const int j = (blockIdx.x & 3) * 256 + threadIdx.x;
    const int c = blockIdx.x >> 2;   // 0..15
    const int b0 = c * 32;
    float acc = 0.f;
#pragma unroll 8
    for (int bo = 0; bo < 32; ++bo)
        acc = fmaf(q[(size_t)(b0 + bo) * L + j], irs[b0 + bo], acc);
    part[(size_t)c * L + j] = acc;
}

// K8: kl[b] = T/S - log(S); cs[j] reduced from 16 partials in-kernel (fixed order).
__global__ __launch_bounds__(256) void kl_kernel(const float* __restrict__ q,
                                                 const float* __restrict__ irs,
                                                 const float* __restrict__ part,
                                                 float* __restrict__ kl) {
    const int b = blockIdx.x;
    const int tid = threadIdx.x;
    const float irsb = irs[b];
    float S = 0.f, T = 0.f;
#pragma unroll
    for (int s = 0; s < 4; ++s) {
        const int j = tid + s * 256;
        float csj = 0.f;
#pragma unroll
        for (int c = 0; c < 16; ++c) csj += part[(size_t)c * L + j];
        const float qq = q[(size_t)b * L + j] * irsb;
        const float ic = 1.0f / csj;
        const float rp = qq * qq * ic;
        S += rp;
        T = fmaf(rp, logf(qq * ic), T);
    }
    __shared__ float sS[256], sT[256];
    sS[tid] = S; sT[tid] = T;
    __syncthreads();
    for (int st = 128; st > 0; st >>= 1) {
        if (tid < st) { sS[tid] += sS[tid + st]; sT[tid] += sT[tid + st]; }
        __syncthreads();
    }
    if (tid == 0) kl[b] = sT[0] / sS[0] - logf(sS[0]);
}

extern "C" void kernel_launch(void* const* d_in, const int* in_sizes, int n_in,
                              void* d_out, int out_size, void* d_ws, size_t ws_size,
                              hipStream_t stream) {
    const float* Zg = (const float*)d_in[0];
    const float* Wg = (const float*)d_in[1];
    const int* step = (const int*)d_in[2];
    float* out = (float*)d_out;          // [0,512): kl_loss, [512,...): delta
    float* ws = (float*)d_ws;

    float* dist = ws + O_DIST;
    float* h    = ws + O_H;
    float* q    = ws + O_Q;
    float* somn = ws + O_SOMN;
    float* irs  = ws + O_IRS;
    float* part = ws + O_PART;   // overlays dead dist buffer

    float* kl    = out;
    float* delta = out + B;

    hipLaunchKernelGGL((dist_kernel<0>), dim3(128), dim3(256), 0, stream, Zg, Wg, dist);
    hipLaunchKernelGGL(argmin_h_kernel, dim3(B), dim3(256), 0, stream, dist, step, h);
    hipLaunchKernelGGL(delta_kernel, dim3(B * 256), dim3(256), 0, stream, Zg, Wg, h, delta);
    hipLaunchKernelGGL(update_kernel, dim3(256), dim3(256), 0, stream, Zg, Wg, h, somn);
    hipLaunchKernelGGL((dist_kernel<1>), dim3(128), dim3(256), 0, stream, Zg, somn, q);
    hipLaunchKernelGGL(rowsum_kernel, dim3(B), dim3(256), 0, stream, q, irs);
    hipLaunchKernelGGL(colsum_part_kernel, dim3(64), dim3(256), 0, stream, q, irs, part);
    hipLaunchKernelGGL(kl_kernel, dim3(B), dim3(256), 0, stream, q, irs, part, kl);
}

// Round 5
// 160.004 us; speedup vs baseline: 1.4365x; 1.2603x over previous
//
#include <hip/hip_runtime.h>
#include <math.h>

// Problem constants
#define B 512
#define E 256
#define L 1024  // 32*32

typedef float f32x4 __attribute__((ext_vector_type(4)));

// Workspace layout (floats)
#define O_DIST 0u            // B*L   (dist^2; dead after argmin_h -> reused for colsum partials)
#define O_H    524288u       // B*L   (eta-scaled h)
#define O_Q    1048576u      // B*L   (raw_q)
#define O_SOMN 1572864u      // L*E
#define O_IRS  1835008u      // B     (1/rowsum)
#define O_PART O_DIST        // 16*L  colsum partials (overlays dead dist)

// ---------------------------------------------------------------------------
// K1/K5: tiled squared-distance matrix out[b, j]
// MODE 0: dist^2.  MODE 1: raw_q = 1/(1+sqrt(dist^2)).
// 64x64 tiles, K-chunks of 64 over E=256, 256 threads, 4x4 micro-tile.
// ---------------------------------------------------------------------------
template <int MODE>
__global__ __launch_bounds__(256) void dist_kernel(const float* __restrict__ Zg,
                                                   const float* __restrict__ Wg,
                                                   float* __restrict__ out) {
    __shared__ float Zs[64][67];
    __shared__ float Ws[64][67];
    const int tid = threadIdx.x;
    const int tb = blockIdx.x >> 4;   // 0..7
    const int tn = blockIdx.x & 15;   // 0..15
    const int b0 = tb * 64, n0 = tn * 64;
    const int ty = tid >> 4, tx = tid & 15;

    float acc[4][4];
#pragma unroll
    for (int i = 0; i < 4; ++i)
#pragma unroll
        for (int j = 0; j < 4; ++j) acc[i][j] = 0.f;

    for (int kc = 0; kc < E; kc += 64) {
        const int c4 = tx * 4;
#pragma unroll
        for (int s = 0; s < 4; ++s) {
            const int r = ty + 16 * s;
            float4 zv = *(const float4*)(Zg + (size_t)(b0 + r) * E + kc + c4);
            Zs[r][c4 + 0] = zv.x; Zs[r][c4 + 1] = zv.y;
            Zs[r][c4 + 2] = zv.z; Zs[r][c4 + 3] = zv.w;
            float4 wv = *(const float4*)(Wg + (size_t)(n0 + r) * E + kc + c4);
            Ws[r][c4 + 0] = wv.x; Ws[r][c4 + 1] = wv.y;
            Ws[r][c4 + 2] = wv.z; Ws[r][c4 + 3] = wv.w;
        }
        __syncthreads();
#pragma unroll 4
        for (int k = 0; k < 64; ++k) {
            float zr[4], wr[4];
#pragma unroll
            for (int i = 0; i < 4; ++i) zr[i] = Zs[ty * 4 + i][k];
#pragma unroll
            for (int j = 0; j < 4; ++j) wr[j] = Ws[tx * 4 + j][k];
#pragma unroll
            for (int i = 0; i < 4; ++i)
#pragma unroll
                for (int j = 0; j < 4; ++j) {
                    float d = zr[i] - wr[j];
                    acc[i][j] = fmaf(d, d, acc[i][j]);
                }
        }
        __syncthreads();
    }
#pragma unroll
    for (int i = 0; i < 4; ++i) {
        const int b = b0 + ty * 4 + i;
        float4 v;
        float r0 = acc[i][0], r1 = acc[i][1], r2 = acc[i][2], r3 = acc[i][3];
        if (MODE == 1) {
            r0 = 1.f / (1.f + sqrtf(r0));
            r1 = 1.f / (1.f + sqrtf(r1));
            r2 = 1.f / (1.f + sqrtf(r2));
            r3 = 1.f / (1.f + sqrtf(r3));
        }
        v.x = r0; v.y = r1; v.z = r2; v.w = r3;
        *(float4*)(out + (size_t)b * L + n0 + tx * 4) = v;
    }
}

// K2: fused per-row argmin (first-index tie-break) + neighborhood h row write
__global__ __launch_bounds__(256) void argmin_h_kernel(const float* __restrict__ dist,
                                                       const int* __restrict__ step,
                                                       float* __restrict__ h) {
    const int b = blockIdx.x;
    const int tid = threadIdx.x;
    float best = 3.4e38f;
    int bi = 0;
#pragma unroll
    for (int s = 0; s < 4; ++s) {
        const int j = tid + s * 256;           // increasing j -> first-min per thread
        const float v = dist[(size_t)b * L + j];
        if (v < best) { best = v; bi = j; }
    }
    __shared__ float sv[256];
    __shared__ int si[256];
    sv[tid] = best; si[tid] = bi;
    __syncthreads();
    for (int s = 128; s > 0; s >>= 1) {
        if (tid < s) {
            float ov = sv[tid + s]; int oi = si[tid + s];
            if (ov < sv[tid] || (ov == sv[tid] && oi < si[tid])) { sv[tid] = ov; si[tid] = oi; }
        }
        __syncthreads();
    }
    __shared__ int su;
    if (tid == 0) su = si[0];
    __syncthreads();

    const int u = su;
    const int ur = u >> 5, uc = u & 31;
    const float n = (float)step[0];
    const float decay = expf(-n * 0.01f);
    const float eta = 0.3f * decay;
    const float sigma = 16.0f * decay;
    const float inv2s2 = 1.0f / (2.0f * sigma * sigma);
#pragma unroll
    for (int s = 0; s < 4; ++s) {
        const int t = tid + s * 256;
        const int i = t >> 5, j = t & 31;
        const float dr = (float)(ur - i), dc = (float)(uc - j);
        h[(size_t)b * L + t] = eta * expf(-(dr * dr + dc * dc) * inv2s2);
    }
}

// K3: delta[b, hw, e] = h_s[b,hw] * (Z[b,e] - SOM[hw,e])   — the 537 MB writer.
// R2-proven structure: 131072 tiny blocks, one 4KB contiguous burst per block,
// NONTEMPORAL stores (R4 A/B: plain cached stores cost ~40-50 µs vs NT).
__global__ __launch_bounds__(256) void delta_kernel(const float* __restrict__ Zg,
                                                    const float* __restrict__ Wg,
                                                    const float* __restrict__ h,
                                                    float* __restrict__ delta) {
    const int bid = blockIdx.x;              // 512 * 256 blocks
    const int b = bid >> 8;
    const int hw = ((bid & 255) << 2) + (threadIdx.x >> 6);
    const int lane = threadIdx.x & 63;
    const float hs = h[(size_t)b * L + hw];
    const float4 z = *(const float4*)(Zg + (size_t)b * E + lane * 4);
    const float4 w = *(const float4*)(Wg + (size_t)hw * E + lane * 4);
    f32x4 o;
    o.x = hs * (z.x - w.x);
    o.y = hs * (z.y - w.y);
    o.z = hs * (z.z - w.z);
    o.w = hs * (z.w - w.w);
    f32x4* dst = (f32x4*)(delta + ((size_t)b * L + hw) * E + lane * 4);
    __builtin_nontemporal_store(o, dst);
}

// K4: SOM_new[hw,e] = SOM + (1/B) * (sum_b h_s*Z - (sum_b h_s) * SOM)
// 1024 blocks (one hw each, ~4 blocks/CU) to hide the serial-b loop latency.
__global__ __launch_bounds__(256) void update_kernel(const float* __restrict__ Zg,
                                                     const float* __restrict__ Wg,
                                                     const float* __restrict__ h,
                                                     float* __restrict__ somn) {
    const int hw = blockIdx.x;
    const int e = threadIdx.x;
    float acc = 0.f, hsum = 0.f;
#pragma unroll 8
    for (int b = 0; b < B; ++b) {
        const float hv = h[(size_t)b * L + hw];   // wave-uniform broadcast
        acc = fmaf(hv, Zg[(size_t)b * E + e], acc);
        hsum += hv;
    }
    const float w = Wg[(size_t)hw * E + e];
    somn[(size_t)hw * E + e] = w + (1.0f / (float)B) * (acc - hsum * w);
}

// K6: irs[b] = 1 / sum_j raw_q[b, j]
__global__ __launch_bounds__(256) void rowsum_kernel(const float* __restrict__ q,
                                                     float* __restrict__ irs) {
    const int b = blockIdx.x;
    const int tid = threadIdx.x;
    float acc = 0.f;
#pragma unroll
    for (int s = 0; s < 4; ++s) acc += q[(size_t)b * L + tid + s * 256];
    __shared__ float sm[256];
    sm[tid] = acc;
    __syncthreads();
    for (int st = 128; st > 0; st >>= 1) {
        if (tid < st) sm[tid] += sm[tid + st];
        __syncthreads();
    }
    if (tid == 0) irs[b] = 1.0f / sm[0];
}

// K7: colsum partials: part[c][j] = sum_{b in chunk c} q[b][j]*irs[b]
__global__ __launch_bounds__(256) void colsum_part_kernel(const float* __restrict__ q,
                                                          const float* __restrict__ irs,
                                                          float* __restrict__ part) {
    const int j = (blockIdx.x & 3) * 256 + threadIdx.x;
    const int c = blockIdx.x >> 2;   // 0..15
    const int b0 = c * 32;
    float acc = 0.f;
#pragma unroll 8
    for (int bo = 0; bo < 32; ++bo)
        acc = fmaf(q[(size_t)(b0 + bo) * L + j], irs[b0 + bo], acc);
    part[(size_t)c * L + j] = acc;
}

// K8: kl[b] = T/S - log(S); cs[j] reduced from 16 partials in-kernel (fixed order).
__global__ __launch_bounds__(256) void kl_kernel(const float* __restrict__ q,
                                                 const float* __restrict__ irs,
                                                 const float* __restrict__ part,
                                                 float* __restrict__ kl) {
    const int b = blockIdx.x;
    const int tid = threadIdx.x;
    const float irsb = irs[b];
    float S = 0.f, T = 0.f;
#pragma unroll
    for (int s = 0; s < 4; ++s) {
        const int j = tid + s * 256;
        float csj = 0.f;
#pragma unroll
        for (int c = 0; c < 16; ++c) csj += part[(size_t)c * L + j];
        const float qq = q[(size_t)b * L + j] * irsb;
        const float ic = 1.0f / csj;
        const float rp = qq * qq * ic;
        S += rp;
        T = fmaf(rp, logf(qq * ic), T);
    }
    __shared__ float sS[256], sT[256];
    sS[tid] = S; sT[tid] = T;
    __syncthreads();
    for (int st = 128; st > 0; st >>= 1) {
        if (tid < st) { sS[tid] += sS[tid + st]; sT[tid] += sT[tid + st]; }
        __syncthreads();
    }
    if (tid == 0) kl[b] = sT[0] / sS[0] - logf(sS[0]);
}

extern "C" void kernel_launch(void* const* d_in, const int* in_sizes, int n_in,
                              void* d_out, int out_size, void* d_ws, size_t ws_size,
                              hipStream_t stream) {
    const float* Zg = (const float*)d_in[0];
    const float* Wg = (const float*)d_in[1];
    const int* step = (const int*)d_in[2];
    float* out = (float*)d_out;          // [0,512): kl_loss, [512,...): delta
    float* ws = (float*)d_ws;

    float* dist = ws + O_DIST;
    float* h    = ws + O_H;
    float* q    = ws + O_Q;
    float* somn = ws + O_SOMN;
    float* irs  = ws + O_IRS;
    float* part = ws + O_PART;   // overlays dead dist buffer

    float* kl    = out;
    float* delta = out + B;

    hipLaunchKernelGGL((dist_kernel<0>), dim3(128), dim3(256), 0, stream, Zg, Wg, dist);
    hipLaunchKernelGGL(argmin_h_kernel, dim3(B), dim3(256), 0, stream, dist, step, h);
    hipLaunchKernelGGL(delta_kernel, dim3(B * 256), dim3(256), 0, stream, Zg, Wg, h, delta);
    hipLaunchKernelGGL(update_kernel, dim3(L), dim3(256), 0, stream, Zg, Wg, h, somn);
    hipLaunchKernelGGL((dist_kernel<1>), dim3(128), dim3(256), 0, stream, Zg, somn, q);
    hipLaunchKernelGGL(rowsum_kernel, dim3(B), dim3(256), 0, stream, q, irs);
    hipLaunchKernelGGL(colsum_part_kernel, dim3(64), dim3(256), 0, stream, q, irs, part);
    hipLaunchKernelGGL(kl_kernel, dim3(B), dim3(256), 0, stream, q, irs, part, kl);
}